// Round 4
// baseline (26923.145 us; speedup 1.0000x reference)
//
#include <hip/hip_runtime.h>
#include <math.h>

// Problem sizes (fixed by setup_inputs)
constexpr int N_V  = 16384;       // original vertices
constexpr int N_F  = 16384;       // original faces (targets for fwd)
constexpr int G_F  = 8192;        // simplified faces (queries for fwd)
constexpr int NS   = 16;          // samples per face
constexpr int NPTS = G_F * NS;    // 131072 sample points (queries for rev)

constexpr int MB = 2;             // 32-row query blocks per wave (64 queries/wave)
constexpr int CT = 4;             // B-tiles per chunk (4 KB), double-buffered

typedef _Float16 half8 __attribute__((ext_vector_type(8)));
typedef float    f32x16 __attribute__((ext_vector_type(16)));

// ---------------- workspace layout (float4 units first, 16B aligned) ----------
constexpr int F4_ACC   = 0;                    // 1  float4: accumulators
constexpr int F4_SB    = 1;                    // [G_F]  simp barycenters x,y,z,|b|^2
constexpr int F4_PTS   = F4_SB + G_F;          // [NPTS] sample points    x,y,z,|p|^2
constexpr int F4_PKV   = F4_PTS + NPTS;        // packed verts: 512 tiles * 64 * 16B
constexpr int F4_PKO   = F4_PKV + 32768;       // packed obary: 512 tiles * 64 * 16B
constexpr int F4_TOTAL = F4_PKO + 32768;
constexpr int WS_MINF  = F4_TOTAL * 4;         // [G_F]  fwd min d^2 (uint bits)
constexpr int WS_MINR  = WS_MINF + G_F;        // [NPTS] rev min d^2 (uint bits)

// Round-9 lesson (round 3 = 25 ms): register-resident streaming with full
// unroll spilled ~64 in-flight dwordx4 dests to scratch (7.9 GB writes,
// 61 GB HBM fetch, MfmaUtil 0.1%).  LDS staging streams with ZERO register
// cost (pending global_load_lds ops have no VGPR dst).  This round keeps
// round-2's proven data path (FETCH 3 MB) but deletes its stall machinery:
// 1-wave workgroups need NO barriers -- chunks are double-buffered and
// synchronized with a counted s_waitcnt vmcnt(4) (wave-private, keeps the
// prefetch in flight; the T3/T4 pattern).  Bonus: 8 KB LDS/block -> 16
// blocks/CU -> 4 waves/SIMD (was 3).
__device__ __forceinline__ f32x16 mfma16(half8 a, half8 b, f32x16 c) {
  return __builtin_amdgcn_mfma_f32_32x32x16_f16(a, b, c, 0, 0, 0);
}

// Pack one target (x,y,z,sq) into B-fragment order (validated: absmax=0):
// col n = lane&31, k = (lane>>5)*8 + j.
// k0-3 = hi(-2x,-2y,-2z,|v|^2), k4-7 = lo residuals, k8-11 = hi again, k12-15 = 0.
__device__ __forceinline__ void pack_target(float x, float y, float z, float sq,
                                            half8* __restrict__ pk, int tile, int n) {
  float ax = -2.0f*x, ay = -2.0f*y, az = -2.0f*z;
  _Float16 hx = (_Float16)ax, hy = (_Float16)ay, hz = (_Float16)az, hw = (_Float16)sq;
  _Float16 lx = (_Float16)(ax - (float)hx), ly = (_Float16)(ay - (float)hy);
  _Float16 lz = (_Float16)(az - (float)hz), lw = (_Float16)(sq - (float)hw);
  half8 h0; h0[0]=hx; h0[1]=hy; h0[2]=hz; h0[3]=hw; h0[4]=lx; h0[5]=ly; h0[6]=lz; h0[7]=lw;
  half8 h1; h1[0]=hx; h1[1]=hy; h1[2]=hz; h1[3]=hw;
  h1[4]=(_Float16)0.0f; h1[5]=(_Float16)0.0f; h1[6]=(_Float16)0.0f; h1[7]=(_Float16)0.0f;
  pk[(size_t)tile*64 + n]      = h0;
  pk[(size_t)tile*64 + 32 + n] = h1;
}

// Fused prep, one thread per sample point.
__global__ void k_prep(const float* __restrict__ ov, const int* __restrict__ of,
                       const float* __restrict__ sv, const int* __restrict__ sf,
                       const float* __restrict__ r1, const float* __restrict__ r2,
                       unsigned int* __restrict__ ws, float4* __restrict__ ws4) {
  int i = blockIdx.x * blockDim.x + threadIdx.x;
  if (i < 4) ws[i] = 0u;                          // acc = 0.0f
  ws[WS_MINR + i] = 0x7f800000u;                  // +inf (grid == NPTS exactly)

  { // sample point i (face verts are 48 KB total -> L1/L2-hot gathers)
    int g = i >> 4;
    int a = sf[3*g], b = sf[3*g+1], c = sf[3*g+2];
    float sr = sqrtf(r1[i]);
    float u = 1.0f - sr;
    float v = sr * (1.0f - r2[i]);
    float w = sr * r2[i];
    float px = u*sv[3*a]   + v*sv[3*b]   + w*sv[3*c];
    float py = u*sv[3*a+1] + v*sv[3*b+1] + w*sv[3*c+1];
    float pz = u*sv[3*a+2] + v*sv[3*b+2] + w*sv[3*c+2];
    (ws4 + F4_PTS)[i] = make_float4(px, py, pz, fmaf(px, px, fmaf(py, py, pz*pz)));
  }
  if (i < G_F) { // simp barycenter (fwd query) + minf init
    ws[WS_MINF + i] = 0x7f800000u;
    int a = sf[3*i], b = sf[3*i+1], c = sf[3*i+2];
    float x = (sv[3*a] + sv[3*b] + sv[3*c]) * (1.0f/3.0f);
    float y = (sv[3*a+1] + sv[3*b+1] + sv[3*c+1]) * (1.0f/3.0f);
    float z = (sv[3*a+2] + sv[3*b+2] + sv[3*c+2]) * (1.0f/3.0f);
    (ws4 + F4_SB)[i] = make_float4(x, y, z, fmaf(x, x, fmaf(y, y, z*z)));
  }
  if (i < N_V) { // packed vertices (rev targets)
    float x = ov[3*i], y = ov[3*i+1], z = ov[3*i+2];
    pack_target(x, y, z, fmaf(x, x, fmaf(y, y, z*z)),
                (half8*)(ws4 + F4_PKV), i >> 5, i & 31);
  }
  if (i < N_F) { // packed orig barycenters (fwd targets)
    int a = of[3*i], b = of[3*i+1], c = of[3*i+2];
    float x = (ov[3*a] + ov[3*b] + ov[3*c]) * (1.0f/3.0f);
    float y = (ov[3*a+1] + ov[3*b+1] + ov[3*c+1]) * (1.0f/3.0f);
    float z = (ov[3*a+2] + ov[3*b+2] + ov[3*c+2]) * (1.0f/3.0f);
    pack_target(x, y, z, fmaf(x, x, fmaf(y, y, z*z)),
                (half8*)(ws4 + F4_PKO), i >> 5, i & 31);
  }
}

// MFMA min-distance kernel: 1-wave workgroups, barrier-free double-buffered
// LDS staging with counted vmcnt.  Each block = 1 wave owns 64 queries
// (MB=2 x 32) and sweeps NCH chunks of CT=4 tiles (4 KB), prefetching chunk
// c+1 while computing chunk c.  vmcnt(4) waits only for the OLD chunk's 4
// loads, keeping the new chunk's loads in flight (never vmcnt(0) mid-loop).
// 8 KB LDS/block -> 16 blocks/CU (HW workgroup cap) = 4 waves/SIMD.
template<int NCH>
__global__ __launch_bounds__(64, 4) void k_min(const float4* __restrict__ q4,
                                               const half8* __restrict__ pk,
                                               unsigned int* __restrict__ minU) {
  __shared__ half8 sB[2][CT * 64];   // 2 x 4 KB
  int lane  = threadIdx.x;           // 0..63 (block == 1 wave)
  int half_ = lane >> 5;
  int m     = lane & 31;
  int qbase = blockIdx.x * 64;
  const half8* src = pk + (size_t)blockIdx.y * (NCH * CT) * 64 + lane;

  // stage chunk 0 -> buf 0 (4 x global_load_lds dwordx4, 1 KB each)
  #pragma unroll
  for (int j = 0; j < CT; ++j) {
    __builtin_amdgcn_global_load_lds(
        (const __attribute__((address_space(1))) unsigned int*)(src + j*64),
        (__attribute__((address_space(3))) unsigned int*)&sB[0][j*64],
        16, 0, 0);
  }

  // A fragments (validated): A[m=lane&31][k=(lane>>5)*8+j]
  // half0: (p_hi,1, p_hi,1)   half1: (p_lo,0, 0,0,0,0)
  half8 afrag[MB];
  float psq[MB];
  #pragma unroll
  for (int mb = 0; mb < MB; ++mb) {
    float4 q = q4[qbase + mb*32 + m];
    psq[mb] = q.w;
    _Float16 hx = (_Float16)q.x, hy = (_Float16)q.y, hz = (_Float16)q.z;
    half8 a;
    if (half_ == 0) {
      a[0]=hx; a[1]=hy; a[2]=hz; a[3]=(_Float16)1.0f;
      a[4]=hx; a[5]=hy; a[6]=hz; a[7]=(_Float16)1.0f;
    } else {
      a[0]=(_Float16)(q.x-(float)hx); a[1]=(_Float16)(q.y-(float)hy);
      a[2]=(_Float16)(q.z-(float)hz); a[3]=(_Float16)0.0f;
      a[4]=(_Float16)0.0f; a[5]=(_Float16)0.0f; a[6]=(_Float16)0.0f; a[7]=(_Float16)0.0f;
    }
    afrag[mb] = a;
  }

  float inf = __uint_as_float(0x7f800000u);
  f32x16 rm0, rm1, zro;
  #pragma unroll
  for (int r = 0; r < 16; ++r) { rm0[r] = inf; rm1[r] = inf; zro[r] = 0.0f; }

  #pragma unroll
  for (int ch = 0; ch < NCH; ++ch) {
    const int buf = ch & 1;
    if (ch + 1 < NCH) {            // prefetch next chunk into other buffer
      const half8* s = src + (size_t)((ch+1) * CT) * 64;
      #pragma unroll
      for (int j = 0; j < CT; ++j) {
        __builtin_amdgcn_global_load_lds(
            (const __attribute__((address_space(1))) unsigned int*)(s + j*64),
            (__attribute__((address_space(3))) unsigned int*)&sB[buf^1][j*64],
            16, 0, 0);
      }
      // wait for the OLD chunk's 4 loads only; new 4 stay in flight
      asm volatile("s_waitcnt vmcnt(4)" ::: "memory");
    } else {
      asm volatile("s_waitcnt vmcnt(0)" ::: "memory");
    }

    #pragma unroll
    for (int t = 0; t < CT; t += 2) {
      half8 cA = sB[buf][t*64 + lane];        // ds_read_b128
      half8 cB = sB[buf][t*64 + 64 + lane];
      // mb=0 pair, reduce, then mb=1 pair: only 2 f32x16 results live at once
      f32x16 dA = mfma16(afrag[0], cA, zro);
      f32x16 dB = mfma16(afrag[0], cB, zro);
      #pragma unroll
      for (int r = 0; r < 16; ++r)
        rm0[r] = fminf(fminf(rm0[r], dA[r]), dB[r]);   // v_min3_f32
      f32x16 eA = mfma16(afrag[1], cA, zro);
      f32x16 eB = mfma16(afrag[1], cB, zro);
      #pragma unroll
      for (int r = 0; r < 16; ++r)
        rm1[r] = fminf(fminf(rm1[r], eA[r]), eB[r]);
    }
  }

  // min across 32 target-columns; write from lane m == row (no q4 reload).
  // C/D: col=lane&31, row=(reg&3)+8*(reg>>2)+4*(lane>>5)   (validated)
  #pragma unroll
  for (int mb = 0; mb < MB; ++mb) {
    #pragma unroll
    for (int r = 0; r < 16; ++r) {
      float v = (mb == 0) ? rm0[r] : rm1[r];
      v = fminf(v, __shfl_xor(v, 1, 64));
      v = fminf(v, __shfl_xor(v, 2, 64));
      v = fminf(v, __shfl_xor(v, 4, 64));
      v = fminf(v, __shfl_xor(v, 8, 64));
      v = fminf(v, __shfl_xor(v, 16, 64));
      int row = (r & 3) + 8*(r >> 2) + 4*half_;
      if (m == row) {
        float d2 = fmaxf(psq[mb] + v, 0.0f);
        atomicMin(&minU[qbase + mb*32 + m], __float_as_uint(d2));
      }
    }
  }
}

__device__ __forceinline__ float waveSum(float v) {
  #pragma unroll
  for (int o = 32; o > 0; o >>= 1) v += __shfl_down(v, o, 64);
  return v;
}
__device__ __forceinline__ float waveMax(float v) {
  #pragma unroll
  for (int o = 32; o > 0; o >>= 1) v = fmaxf(v, __shfl_down(v, o, 64));
  return v;
}

__global__ void k_reduce(const float* __restrict__ probs, const float* __restrict__ minf,
                         const float* __restrict__ minr, float* __restrict__ acc) {
  int tid = blockIdx.x * blockDim.x + threadIdx.x;
  int stride = gridDim.x * blockDim.x;
  float sf = 0.0f, sr = 0.0f, mx = 0.0f;
  for (int i = tid; i < NPTS; i += stride) {
    float d = sqrtf(fmaxf(minr[i], 1e-12f));
    sr = fmaf(probs[i >> 4], d, sr);
    mx = fmaxf(mx, d);
    if (i < G_F) {
      float df = sqrtf(fmaxf(minf[i], 1e-12f));
      sf = fmaf(probs[i], df, sf);
      sf = fmaf(1e-4f, 1.0f - probs[i], sf);
    }
  }
  __shared__ float lf[4], lr[4], lm[4];
  int lane = threadIdx.x & 63, wid = threadIdx.x >> 6;
  sf = waveSum(sf); sr = waveSum(sr); mx = waveMax(mx);
  if (lane == 0) { lf[wid] = sf; lr[wid] = sr; lm[wid] = mx; }
  __syncthreads();
  if (wid == 0) {
    float a = (lane < 4) ? lf[lane] : 0.0f;
    float b = (lane < 4) ? lr[lane] : 0.0f;
    float c = (lane < 4) ? lm[lane] : 0.0f;
    a = waveSum(a); b = waveSum(b); c = waveMax(c);
    if (lane == 0) {
      atomicAdd(&acc[0], a);
      atomicAdd(&acc[1], b);
      atomicMax((unsigned int*)&acc[2], __float_as_uint(c));
    }
  }
}

__global__ void k_final(const float* __restrict__ acc, float* __restrict__ out) {
  float maxd = acc[2] + 1e-8f;
  out[0] = acc[0] + acc[1] * 0.1f / maxd;
}

extern "C" void kernel_launch(void* const* d_in, const int* in_sizes, int n_in,
                              void* d_out, int out_size, void* d_ws, size_t ws_size,
                              hipStream_t stream) {
  const float* ov    = (const float*)d_in[0];
  const int*   of    = (const int*)  d_in[1];
  const float* sv    = (const float*)d_in[2];
  const int*   sfc   = (const int*)  d_in[3];
  const float* probs = (const float*)d_in[4];
  const float* r1    = (const float*)d_in[5];
  const float* r2    = (const float*)d_in[6];
  float*  ws  = (float*)d_ws;
  float4* ws4 = (float4*)d_ws;
  float*  out = (float*)d_out;

  float*        acc   = ws;
  float4*       sb4   = ws4 + F4_SB;
  float4*       pts4  = ws4 + F4_PTS;
  half8*        pkV   = (half8*)(ws4 + F4_PKV);
  half8*        pkO   = (half8*)(ws4 + F4_PKO);
  unsigned int* minfU = (unsigned int*)(ws + WS_MINF);
  unsigned int* minrU = (unsigned int*)(ws + WS_MINR);
  const float*  minfF = ws + WS_MINF;
  const float*  minrF = ws + WS_MINR;

  k_prep<<<NPTS/256, 256, 0, stream>>>(ov, of, sv, sfc, r1, r2,
                                       (unsigned int*)ws, ws4);
  // fwd: 8192 queries (128 wave-blocks), 512 tiles split 16 ways -> NCH=8
  k_min<8><<<dim3(G_F/64, 16), 64, 0, stream>>>(sb4, pkO, minfU);
  // rev: 131072 queries (2048 wave-blocks), 512 tiles split 8 ways -> NCH=16
  k_min<16><<<dim3(NPTS/64, 8), 64, 0, stream>>>(pts4, pkV, minrU);
  k_reduce<<<256, 256, 0, stream>>>(probs, minfF, minrF, acc);
  k_final<<<1, 1, 0, stream>>>(acc, out);
}

// Round 5
// 174.836 us; speedup vs baseline: 153.9912x; 153.9912x over previous
//
#include <hip/hip_runtime.h>
#include <math.h>

// Problem sizes (fixed by setup_inputs)
constexpr int N_V  = 16384;       // original vertices
constexpr int N_F  = 16384;       // original faces (targets for fwd)
constexpr int G_F  = 8192;        // simplified faces (queries for fwd)
constexpr int NS   = 16;          // samples per face
constexpr int NPTS = G_F * NS;    // 131072 sample points (queries for rev)

constexpr int MB    = 2;          // 32-row query blocks per wave (64 queries/wave)
constexpr int CT    = 16;         // B-tiles per LDS chunk (16 KB), double-buffered

typedef _Float16 half8 __attribute__((ext_vector_type(8)));
typedef float    f32x16 __attribute__((ext_vector_type(16)));

// ---------------- workspace layout (float4 units first, 16B aligned) ----------
constexpr int F4_ACC   = 0;                    // 1  float4: accumulators
constexpr int F4_SB    = 1;                    // [G_F]  simp barycenters x,y,z,|b|^2
constexpr int F4_PTS   = F4_SB + G_F;          // [NPTS] sample points    x,y,z,|p|^2
constexpr int F4_PKV   = F4_PTS + NPTS;        // packed verts: 512 tiles * 64 * 16B
constexpr int F4_PKO   = F4_PKV + 32768;       // packed obary: 512 tiles * 64 * 16B
constexpr int F4_TOTAL = F4_PKO + 32768;
constexpr int WS_MINF  = F4_TOTAL * 4;         // [G_F]  fwd min d^2 (uint bits)
constexpr int WS_MINR  = WS_MINF + G_F;        // [NPTS] rev min d^2 (uint bits)

// Round-10 diagnosis chain:
//  - r3/r4 (template full-unroll of the outer loop) ballooned live ranges ->
//    tuple spill to scratch -> 60+ GB HBM, 25 ms.  Outer loops stay
//    runtime-bounded; this file is the r2 base (93 us rev, FETCH 3 MB).
//  - r2's 123 VALU instr/unit (vs 32 min3 accounted) + occupancy 37% both
//    resolve as: unified pressure ~164 = 52 arch + ~112 AGPR (512/164 -> 3
//    waves/SIMD), MFMA dsts in AGPRs, and v_min3 cannot read AGPRs -> every
//    result element pays an accvgpr crossing (64 reads + rm writes).
//  - THIS ROUND'S ONE LEVER: __launch_bounds__(256, 4) caps unified regs at
//    128/wave.  Essential liveness ~110, so the only way to fit is
//    (near-)all-arch allocation: kills the crossing tax AND gives 4
//    waves/SIMD.  Tripwire: WRITE_SIZE >> 100 MB means spill -> revert to 3.
__device__ __forceinline__ f32x16 mfma16(half8 a, half8 b, f32x16 c) {
  return __builtin_amdgcn_mfma_f32_32x32x16_f16(a, b, c, 0, 0, 0);
}

// Pack one target (x,y,z,sq) into B-fragment order (validated: absmax=0):
// col n = lane&31, k = (lane>>5)*8 + j.
// k0-3 = hi(-2x,-2y,-2z,|v|^2), k4-7 = lo residuals, k8-11 = hi again, k12-15 = 0.
__device__ __forceinline__ void pack_target(float x, float y, float z, float sq,
                                            half8* __restrict__ pk, int tile, int n) {
  float ax = -2.0f*x, ay = -2.0f*y, az = -2.0f*z;
  _Float16 hx = (_Float16)ax, hy = (_Float16)ay, hz = (_Float16)az, hw = (_Float16)sq;
  _Float16 lx = (_Float16)(ax - (float)hx), ly = (_Float16)(ay - (float)hy);
  _Float16 lz = (_Float16)(az - (float)hz), lw = (_Float16)(sq - (float)hw);
  half8 h0; h0[0]=hx; h0[1]=hy; h0[2]=hz; h0[3]=hw; h0[4]=lx; h0[5]=ly; h0[6]=lz; h0[7]=lw;
  half8 h1; h1[0]=hx; h1[1]=hy; h1[2]=hz; h1[3]=hw;
  h1[4]=(_Float16)0.0f; h1[5]=(_Float16)0.0f; h1[6]=(_Float16)0.0f; h1[7]=(_Float16)0.0f;
  pk[(size_t)tile*64 + n]      = h0;
  pk[(size_t)tile*64 + 32 + n] = h1;
}

// Fused prep, one thread per sample point.
__global__ void k_prep(const float* __restrict__ ov, const int* __restrict__ of,
                       const float* __restrict__ sv, const int* __restrict__ sf,
                       const float* __restrict__ r1, const float* __restrict__ r2,
                       unsigned int* __restrict__ ws, float4* __restrict__ ws4) {
  int i = blockIdx.x * blockDim.x + threadIdx.x;
  if (i < 4) ws[i] = 0u;                          // acc = 0.0f
  ws[WS_MINR + i] = 0x7f800000u;                  // +inf (grid == NPTS exactly)

  { // sample point i (face verts are 48 KB total -> L1/L2-hot gathers)
    int g = i >> 4;
    int a = sf[3*g], b = sf[3*g+1], c = sf[3*g+2];
    float sr = sqrtf(r1[i]);
    float u = 1.0f - sr;
    float v = sr * (1.0f - r2[i]);
    float w = sr * r2[i];
    float px = u*sv[3*a]   + v*sv[3*b]   + w*sv[3*c];
    float py = u*sv[3*a+1] + v*sv[3*b+1] + w*sv[3*c+1];
    float pz = u*sv[3*a+2] + v*sv[3*b+2] + w*sv[3*c+2];
    (ws4 + F4_PTS)[i] = make_float4(px, py, pz, fmaf(px, px, fmaf(py, py, pz*pz)));
  }
  if (i < G_F) { // simp barycenter (fwd query) + minf init
    ws[WS_MINF + i] = 0x7f800000u;
    int a = sf[3*i], b = sf[3*i+1], c = sf[3*i+2];
    float x = (sv[3*a] + sv[3*b] + sv[3*c]) * (1.0f/3.0f);
    float y = (sv[3*a+1] + sv[3*b+1] + sv[3*c+1]) * (1.0f/3.0f);
    float z = (sv[3*a+2] + sv[3*b+2] + sv[3*c+2]) * (1.0f/3.0f);
    (ws4 + F4_SB)[i] = make_float4(x, y, z, fmaf(x, x, fmaf(y, y, z*z)));
  }
  if (i < N_V) { // packed vertices (rev targets)
    float x = ov[3*i], y = ov[3*i+1], z = ov[3*i+2];
    pack_target(x, y, z, fmaf(x, x, fmaf(y, y, z*z)),
                (half8*)(ws4 + F4_PKV), i >> 5, i & 31);
  }
  if (i < N_F) { // packed orig barycenters (fwd targets)
    int a = of[3*i], b = of[3*i+1], c = of[3*i+2];
    float x = (ov[3*a] + ov[3*b] + ov[3*c]) * (1.0f/3.0f);
    float y = (ov[3*a+1] + ov[3*b+1] + ov[3*c+1]) * (1.0f/3.0f);
    float z = (ov[3*a+2] + ov[3*b+2] + ov[3*c+2]) * (1.0f/3.0f);
    pack_target(x, y, z, fmaf(x, x, fmaf(y, y, z*z)),
                (half8*)(ws4 + F4_PKO), i >> 5, i & 31);
  }
}

// MFMA min-distance kernel, LDS-staged, builtin MFMA (compiler-scheduled).
// Block = 256 queries (4 waves x 64).  Sweeps nchunks chunks of CT=16 B-tiles
// (runtime-bounded loop: r3/r4 proved full unroll of this loop spills);
// chunks double-buffered in LDS (2 x 16 KB), prefetch of chunk c+1 issued
// right after the barrier opening chunk c.
// launch_bounds (256,4): unified (arch+AGPR) cap = 128 regs/wave.  Forces
// the allocator out of the arch/AGPR split (52+112 at cap 168) that made
// every min3 pay accvgpr crossings; also 4 waves/SIMD instead of 3.
__global__ __launch_bounds__(256, 4) void k_min(const float4* __restrict__ q4,
                                                const half8* __restrict__ pk,
                                                unsigned int* __restrict__ minU,
                                                int nchunks) {
  __shared__ half8 sB[2][CT * 64];   // 2 x 16 KB
  int lane  = threadIdx.x & 63;
  int wave  = threadIdx.x >> 6;
  int half_ = lane >> 5;
  int m     = lane & 31;
  int qbase = blockIdx.x * 256 + wave * (32 * MB);
  int tbase = blockIdx.y * nchunks * CT;

  // prologue stage: chunk 0 -> buf 0 (wave w loads tiles w, w+4, w+8, w+12)
  {
    const half8* src = pk + (size_t)(tbase + wave) * 64 + lane;
    #pragma unroll
    for (int j = 0; j < CT/4; ++j) {
      __builtin_amdgcn_global_load_lds(
          (const __attribute__((address_space(1))) unsigned int*)(src + (size_t)j*256),
          (__attribute__((address_space(3))) unsigned int*)&sB[0][(wave + 4*j) * 64],
          16, 0, 0);
    }
  }

  // A fragments (validated): A[m=lane&31][k=(lane>>5)*8+j]
  // half0: (p_hi,1, p_hi,1)   half1: (p_lo,0, 0,0,0,0)
  half8 afrag[MB];
  float psq[MB];
  #pragma unroll
  for (int mb = 0; mb < MB; ++mb) {
    float4 q = q4[qbase + mb*32 + m];
    psq[mb] = q.w;
    _Float16 hx = (_Float16)q.x, hy = (_Float16)q.y, hz = (_Float16)q.z;
    half8 a;
    if (half_ == 0) {
      a[0]=hx; a[1]=hy; a[2]=hz; a[3]=(_Float16)1.0f;
      a[4]=hx; a[5]=hy; a[6]=hz; a[7]=(_Float16)1.0f;
    } else {
      a[0]=(_Float16)(q.x-(float)hx); a[1]=(_Float16)(q.y-(float)hy);
      a[2]=(_Float16)(q.z-(float)hz); a[3]=(_Float16)0.0f;
      a[4]=(_Float16)0.0f; a[5]=(_Float16)0.0f; a[6]=(_Float16)0.0f; a[7]=(_Float16)0.0f;
    }
    afrag[mb] = a;
  }

  float inf = __uint_as_float(0x7f800000u);
  f32x16 rm0, rm1, zro;
  #pragma unroll
  for (int r = 0; r < 16; ++r) { rm0[r] = inf; rm1[r] = inf; zro[r] = 0.0f; }

  for (int ch = 0; ch < nchunks; ++ch) {
    const int b = ch & 1;
    __syncthreads();               // own vmcnt drained -> buf b resident;
                                   // all waves done reading buf b^1
    if (ch + 1 < nchunks) {        // stage next chunk into the other buffer
      const half8* src = pk + (size_t)(tbase + (ch+1)*CT + wave) * 64 + lane;
      #pragma unroll
      for (int j = 0; j < CT/4; ++j) {
        __builtin_amdgcn_global_load_lds(
            (const __attribute__((address_space(1))) unsigned int*)(src + (size_t)j*256),
            (__attribute__((address_space(3))) unsigned int*)&sB[b^1][(wave + 4*j) * 64],
            16, 0, 0);
      }
    }

    #pragma unroll
    for (int t = 0; t < CT; t += 2) {
      half8 cA = sB[b][t*64 + lane];        // ds_read_b128
      half8 cB = sB[b][t*64 + 64 + lane];
      // mb=0 pair, reduce, then mb=1 pair: only 2 f32x16 results live at once
      f32x16 dA = mfma16(afrag[0], cA, zro);
      f32x16 dB = mfma16(afrag[0], cB, zro);
      #pragma unroll
      for (int r = 0; r < 16; ++r)
        rm0[r] = fminf(fminf(rm0[r], dA[r]), dB[r]);   // v_min3_f32
      f32x16 eA = mfma16(afrag[1], cA, zro);
      f32x16 eB = mfma16(afrag[1], cB, zro);
      #pragma unroll
      for (int r = 0; r < 16; ++r)
        rm1[r] = fminf(fminf(rm1[r], eA[r]), eB[r]);
    }
  }

  // min across 32 target-columns; write from lane m == row (no q4 reload).
  // C/D: col=lane&31, row=(reg&3)+8*(reg>>2)+4*(lane>>5)   (validated)
  #pragma unroll
  for (int mb = 0; mb < MB; ++mb) {
    #pragma unroll
    for (int r = 0; r < 16; ++r) {
      float v = (mb == 0) ? rm0[r] : rm1[r];
      v = fminf(v, __shfl_xor(v, 1, 64));
      v = fminf(v, __shfl_xor(v, 2, 64));
      v = fminf(v, __shfl_xor(v, 4, 64));
      v = fminf(v, __shfl_xor(v, 8, 64));
      v = fminf(v, __shfl_xor(v, 16, 64));
      int row = (r & 3) + 8*(r >> 2) + 4*half_;
      if (m == row) {
        float d2 = fmaxf(psq[mb] + v, 0.0f);
        atomicMin(&minU[qbase + mb*32 + m], __float_as_uint(d2));
      }
    }
  }
}

__device__ __forceinline__ float waveSum(float v) {
  #pragma unroll
  for (int o = 32; o > 0; o >>= 1) v += __shfl_down(v, o, 64);
  return v;
}
__device__ __forceinline__ float waveMax(float v) {
  #pragma unroll
  for (int o = 32; o > 0; o >>= 1) v = fmaxf(v, __shfl_down(v, o, 64));
  return v;
}

__global__ void k_reduce(const float* __restrict__ probs, const float* __restrict__ minf,
                         const float* __restrict__ minr, float* __restrict__ acc) {
  int tid = blockIdx.x * blockDim.x + threadIdx.x;
  int stride = gridDim.x * blockDim.x;
  float sf = 0.0f, sr = 0.0f, mx = 0.0f;
  for (int i = tid; i < NPTS; i += stride) {
    float d = sqrtf(fmaxf(minr[i], 1e-12f));
    sr = fmaf(probs[i >> 4], d, sr);
    mx = fmaxf(mx, d);
    if (i < G_F) {
      float df = sqrtf(fmaxf(minf[i], 1e-12f));
      sf = fmaf(probs[i], df, sf);
      sf = fmaf(1e-4f, 1.0f - probs[i], sf);
    }
  }
  __shared__ float lf[4], lr[4], lm[4];
  int lane = threadIdx.x & 63, wid = threadIdx.x >> 6;
  sf = waveSum(sf); sr = waveSum(sr); mx = waveMax(mx);
  if (lane == 0) { lf[wid] = sf; lr[wid] = sr; lm[wid] = mx; }
  __syncthreads();
  if (wid == 0) {
    float a = (lane < 4) ? lf[lane] : 0.0f;
    float b = (lane < 4) ? lr[lane] : 0.0f;
    float c = (lane < 4) ? lm[lane] : 0.0f;
    a = waveSum(a); b = waveSum(b); c = waveMax(c);
    if (lane == 0) {
      atomicAdd(&acc[0], a);
      atomicAdd(&acc[1], b);
      atomicMax((unsigned int*)&acc[2], __float_as_uint(c));
    }
  }
}

__global__ void k_final(const float* __restrict__ acc, float* __restrict__ out) {
  float maxd = acc[2] + 1e-8f;
  out[0] = acc[0] + acc[1] * 0.1f / maxd;
}

extern "C" void kernel_launch(void* const* d_in, const int* in_sizes, int n_in,
                              void* d_out, int out_size, void* d_ws, size_t ws_size,
                              hipStream_t stream) {
  const float* ov    = (const float*)d_in[0];
  const int*   of    = (const int*)  d_in[1];
  const float* sv    = (const float*)d_in[2];
  const int*   sfc   = (const int*)  d_in[3];
  const float* probs = (const float*)d_in[4];
  const float* r1    = (const float*)d_in[5];
  const float* r2    = (const float*)d_in[6];
  float*  ws  = (float*)d_ws;
  float4* ws4 = (float4*)d_ws;
  float*  out = (float*)d_out;

  float*        acc   = ws;
  float4*       sb4   = ws4 + F4_SB;
  float4*       pts4  = ws4 + F4_PTS;
  half8*        pkV   = (half8*)(ws4 + F4_PKV);
  half8*        pkO   = (half8*)(ws4 + F4_PKO);
  unsigned int* minfU = (unsigned int*)(ws + WS_MINF);
  unsigned int* minrU = (unsigned int*)(ws + WS_MINR);
  const float*  minfF = ws + WS_MINF;
  const float*  minrF = ws + WS_MINR;

  k_prep<<<NPTS/256, 256, 0, stream>>>(ov, of, sv, sfc, r1, r2,
                                       (unsigned int*)ws, ws4);
  // fwd: 8192 queries, 512 obary tiles; 32 x 16 blocks, 2 chunks each
  k_min<<<dim3(G_F/256, 16), 256, 0, stream>>>(sb4, pkO, minfU, 2);
  // rev: 131072 queries, 512 vert tiles; 512 x 8 blocks, 4 chunks each
  k_min<<<dim3(NPTS/256, 8), 256, 0, stream>>>(pts4, pkV, minrU, 4);
  k_reduce<<<256, 256, 0, stream>>>(probs, minfF, minrF, acc);
  k_final<<<1, 1, 0, stream>>>(acc, out);
}

// Round 6
// 167.450 us; speedup vs baseline: 160.7836x; 1.0441x over previous
//
#include <hip/hip_runtime.h>
#include <math.h>

// Problem sizes (fixed by setup_inputs)
constexpr int N_V  = 16384;       // original vertices
constexpr int N_F  = 16384;       // original faces (targets for fwd)
constexpr int G_F  = 8192;        // simplified faces (queries for fwd)
constexpr int NS   = 16;          // samples per face
constexpr int NPTS = G_F * NS;    // 131072 sample points (queries for rev)

constexpr int MB    = 2;          // 32-row query blocks per wave (64 queries/wave)
constexpr int CT    = 16;         // B-tiles per LDS chunk (16 KB), double-buffered

typedef _Float16 half8 __attribute__((ext_vector_type(8)));
typedef float    f32x16 __attribute__((ext_vector_type(16)));

// ---------------- workspace layout (float4 units first, 16B aligned) ----------
constexpr int F4_ACC   = 0;                    // 1  float4: accumulators
constexpr int F4_SB    = 1;                    // [G_F]  simp barycenters x,y,z,|b|^2
constexpr int F4_PTS   = F4_SB + G_F;          // [NPTS] sample points    x,y,z,|p|^2
constexpr int F4_PKV   = F4_PTS + NPTS;        // packed verts: 512 tiles * 64 * 16B
constexpr int F4_PKO   = F4_PKV + 32768;       // packed obary: 512 tiles * 64 * 16B
constexpr int F4_TOTAL = F4_PKO + 32768;
constexpr int WS_MINF  = F4_TOTAL * 4;         // [G_F]  fwd min d^2 (uint bits)
constexpr int WS_MINR  = WS_MINF + G_F;        // [NPTS] rev min d^2 (uint bits)

// Round-11 corrected model: VALUBusy INCLUDES MFMA cycles (SQ counts MFMA
// under the VALU instruction class).  Non-MFMA VALU = 56-30 = 26% = ~56
// instr/unit = exactly the source's 32 min3 + overhead.  No accvgpr tax
// exists (CDNA4 VALU reads AGPRs directly); r3-r5's register theories were
// chasing a phantom.  Real picture: MFMA 30% + VALU 26% -> ~44% of cycles
// the SIMD issues NOTHING, and MfmaUtil == the single-wave MFMA fraction,
// i.e. resident waves' phases don't overlap (2-barrier-structure plateau).
// This round (additive, hot loop untouched):
//  1) fwd+rev merged into ONE dispatch (fwd alone had max 2 waves/SIMD and
//     its own launch gap; wall 174.8 vs sum-of-dispatches ~142 -> ~33 us of
//     gaps/tails).  Block-uniform pointer select, both sides nchunks=4.
//  2) pair-reuse sequencing in the t-loop to trim unified liveness.
__device__ __forceinline__ f32x16 mfma16(half8 a, half8 b, f32x16 c) {
  return __builtin_amdgcn_mfma_f32_32x32x16_f16(a, b, c, 0, 0, 0);
}

// Pack one target (x,y,z,sq) into B-fragment order (validated: absmax=0):
// col n = lane&31, k = (lane>>5)*8 + j.
// k0-3 = hi(-2x,-2y,-2z,|v|^2), k4-7 = lo residuals, k8-11 = hi again, k12-15 = 0.
__device__ __forceinline__ void pack_target(float x, float y, float z, float sq,
                                            half8* __restrict__ pk, int tile, int n) {
  float ax = -2.0f*x, ay = -2.0f*y, az = -2.0f*z;
  _Float16 hx = (_Float16)ax, hy = (_Float16)ay, hz = (_Float16)az, hw = (_Float16)sq;
  _Float16 lx = (_Float16)(ax - (float)hx), ly = (_Float16)(ay - (float)hy);
  _Float16 lz = (_Float16)(az - (float)hz), lw = (_Float16)(sq - (float)hw);
  half8 h0; h0[0]=hx; h0[1]=hy; h0[2]=hz; h0[3]=hw; h0[4]=lx; h0[5]=ly; h0[6]=lz; h0[7]=lw;
  half8 h1; h1[0]=hx; h1[1]=hy; h1[2]=hz; h1[3]=hw;
  h1[4]=(_Float16)0.0f; h1[5]=(_Float16)0.0f; h1[6]=(_Float16)0.0f; h1[7]=(_Float16)0.0f;
  pk[(size_t)tile*64 + n]      = h0;
  pk[(size_t)tile*64 + 32 + n] = h1;
}

// Fused prep, one thread per sample point.
__global__ void k_prep(const float* __restrict__ ov, const int* __restrict__ of,
                       const float* __restrict__ sv, const int* __restrict__ sf,
                       const float* __restrict__ r1, const float* __restrict__ r2,
                       unsigned int* __restrict__ ws, float4* __restrict__ ws4) {
  int i = blockIdx.x * blockDim.x + threadIdx.x;
  if (i < 4) ws[i] = 0u;                          // acc = 0.0f
  ws[WS_MINR + i] = 0x7f800000u;                  // +inf (grid == NPTS exactly)

  { // sample point i (face verts are 48 KB total -> L1/L2-hot gathers)
    int g = i >> 4;
    int a = sf[3*g], b = sf[3*g+1], c = sf[3*g+2];
    float sr = sqrtf(r1[i]);
    float u = 1.0f - sr;
    float v = sr * (1.0f - r2[i]);
    float w = sr * r2[i];
    float px = u*sv[3*a]   + v*sv[3*b]   + w*sv[3*c];
    float py = u*sv[3*a+1] + v*sv[3*b+1] + w*sv[3*c+1];
    float pz = u*sv[3*a+2] + v*sv[3*b+2] + w*sv[3*c+2];
    (ws4 + F4_PTS)[i] = make_float4(px, py, pz, fmaf(px, px, fmaf(py, py, pz*pz)));
  }
  if (i < G_F) { // simp barycenter (fwd query) + minf init
    ws[WS_MINF + i] = 0x7f800000u;
    int a = sf[3*i], b = sf[3*i+1], c = sf[3*i+2];
    float x = (sv[3*a] + sv[3*b] + sv[3*c]) * (1.0f/3.0f);
    float y = (sv[3*a+1] + sv[3*b+1] + sv[3*c+1]) * (1.0f/3.0f);
    float z = (sv[3*a+2] + sv[3*b+2] + sv[3*c+2]) * (1.0f/3.0f);
    (ws4 + F4_SB)[i] = make_float4(x, y, z, fmaf(x, x, fmaf(y, y, z*z)));
  }
  if (i < N_V) { // packed vertices (rev targets)
    float x = ov[3*i], y = ov[3*i+1], z = ov[3*i+2];
    pack_target(x, y, z, fmaf(x, x, fmaf(y, y, z*z)),
                (half8*)(ws4 + F4_PKV), i >> 5, i & 31);
  }
  if (i < N_F) { // packed orig barycenters (fwd targets)
    int a = of[3*i], b = of[3*i+1], c = of[3*i+2];
    float x = (ov[3*a] + ov[3*b] + ov[3*c]) * (1.0f/3.0f);
    float y = (ov[3*a+1] + ov[3*b+1] + ov[3*c+1]) * (1.0f/3.0f);
    float z = (ov[3*a+2] + ov[3*b+2] + ov[3*c+2]) * (1.0f/3.0f);
    pack_target(x, y, z, fmaf(x, x, fmaf(y, y, z*z)),
                (half8*)(ws4 + F4_PKO), i >> 5, i & 31);
  }
}

// MFMA min-distance kernel, LDS-staged, builtin MFMA (compiler-scheduled).
// MERGED dispatch: blocks with blockIdx.x < NPTS/256 process rev queries
// (sample points vs packed verts); the rest process fwd queries (simp
// barycenters vs packed obary).  Block-uniform select, same nchunks=4.
// Block = 256 queries (4 waves x 64); sweeps nchunks chunks of CT=16
// B-tiles (runtime-bounded loop: r3/r4 proved unrolling this spills),
// double-buffered in LDS, prefetch of chunk c+1 issued right after the
// barrier opening chunk c.
__global__ __launch_bounds__(256, 4) void k_min(
    const float4* __restrict__ q4r, const half8* __restrict__ pkr,
    unsigned int* __restrict__ mUr,
    const float4* __restrict__ q4f, const half8* __restrict__ pkf,
    unsigned int* __restrict__ mUf, int nchunks) {
  __shared__ half8 sB[2][CT * 64];   // 2 x 16 KB
  int lane  = threadIdx.x & 63;
  int wave  = threadIdx.x >> 6;
  int half_ = lane >> 5;
  int m     = lane & 31;

  const bool isFwd = (blockIdx.x >= (unsigned)(NPTS/256));
  const float4*  q4   = isFwd ? q4f : q4r;
  const half8*   pk   = isFwd ? pkf : pkr;
  unsigned int*  minU = isFwd ? mUf : mUr;
  int bx    = isFwd ? (int)blockIdx.x - NPTS/256 : (int)blockIdx.x;
  int qbase = bx * 256 + wave * (32 * MB);
  int tbase = blockIdx.y * nchunks * CT;

  // prologue stage: chunk 0 -> buf 0 (wave w loads tiles w, w+4, w+8, w+12)
  {
    const half8* src = pk + (size_t)(tbase + wave) * 64 + lane;
    #pragma unroll
    for (int j = 0; j < CT/4; ++j) {
      __builtin_amdgcn_global_load_lds(
          (const __attribute__((address_space(1))) unsigned int*)(src + (size_t)j*256),
          (__attribute__((address_space(3))) unsigned int*)&sB[0][(wave + 4*j) * 64],
          16, 0, 0);
    }
  }

  // A fragments (validated): A[m=lane&31][k=(lane>>5)*8+j]
  // half0: (p_hi,1, p_hi,1)   half1: (p_lo,0, 0,0,0,0)
  half8 afrag[MB];
  float psq[MB];
  #pragma unroll
  for (int mb = 0; mb < MB; ++mb) {
    float4 q = q4[qbase + mb*32 + m];
    psq[mb] = q.w;
    _Float16 hx = (_Float16)q.x, hy = (_Float16)q.y, hz = (_Float16)q.z;
    half8 a;
    if (half_ == 0) {
      a[0]=hx; a[1]=hy; a[2]=hz; a[3]=(_Float16)1.0f;
      a[4]=hx; a[5]=hy; a[6]=hz; a[7]=(_Float16)1.0f;
    } else {
      a[0]=(_Float16)(q.x-(float)hx); a[1]=(_Float16)(q.y-(float)hy);
      a[2]=(_Float16)(q.z-(float)hz); a[3]=(_Float16)0.0f;
      a[4]=(_Float16)0.0f; a[5]=(_Float16)0.0f; a[6]=(_Float16)0.0f; a[7]=(_Float16)0.0f;
    }
    afrag[mb] = a;
  }

  float inf = __uint_as_float(0x7f800000u);
  f32x16 rm0, rm1, zro;
  #pragma unroll
  for (int r = 0; r < 16; ++r) { rm0[r] = inf; rm1[r] = inf; zro[r] = 0.0f; }

  for (int ch = 0; ch < nchunks; ++ch) {
    const int b = ch & 1;
    __syncthreads();               // own vmcnt drained -> buf b resident;
                                   // all waves done reading buf b^1
    if (ch + 1 < nchunks) {        // stage next chunk into the other buffer
      const half8* src = pk + (size_t)(tbase + (ch+1)*CT + wave) * 64 + lane;
      #pragma unroll
      for (int j = 0; j < CT/4; ++j) {
        __builtin_amdgcn_global_load_lds(
            (const __attribute__((address_space(1))) unsigned int*)(src + (size_t)j*256),
            (__attribute__((address_space(3))) unsigned int*)&sB[b^1][(wave + 4*j) * 64],
            16, 0, 0);
      }
    }

    #pragma unroll
    for (int t = 0; t < CT; t += 2) {
      half8 cA = sB[b][t*64 + lane];        // ds_read_b128
      half8 cB = sB[b][t*64 + 64 + lane];
      // pair-reuse sequencing: dA/dB reused for the second query block so
      // at most 2 result tuples are live at any point
      f32x16 dA = mfma16(afrag[0], cA, zro);
      f32x16 dB = mfma16(afrag[0], cB, zro);
      #pragma unroll
      for (int r = 0; r < 16; ++r)
        rm0[r] = fminf(fminf(rm0[r], dA[r]), dB[r]);   // v_min3_f32
      dA = mfma16(afrag[1], cA, zro);
      dB = mfma16(afrag[1], cB, zro);
      #pragma unroll
      for (int r = 0; r < 16; ++r)
        rm1[r] = fminf(fminf(rm1[r], dA[r]), dB[r]);
    }
  }

  // min across 32 target-columns; write from lane m == row (no q4 reload).
  // C/D: col=lane&31, row=(reg&3)+8*(reg>>2)+4*(lane>>5)   (validated)
  #pragma unroll
  for (int mb = 0; mb < MB; ++mb) {
    #pragma unroll
    for (int r = 0; r < 16; ++r) {
      float v = (mb == 0) ? rm0[r] : rm1[r];
      v = fminf(v, __shfl_xor(v, 1, 64));
      v = fminf(v, __shfl_xor(v, 2, 64));
      v = fminf(v, __shfl_xor(v, 4, 64));
      v = fminf(v, __shfl_xor(v, 8, 64));
      v = fminf(v, __shfl_xor(v, 16, 64));
      int row = (r & 3) + 8*(r >> 2) + 4*half_;
      if (m == row) {
        float d2 = fmaxf(psq[mb] + v, 0.0f);
        atomicMin(&minU[qbase + mb*32 + m], __float_as_uint(d2));
      }
    }
  }
}

__device__ __forceinline__ float waveSum(float v) {
  #pragma unroll
  for (int o = 32; o > 0; o >>= 1) v += __shfl_down(v, o, 64);
  return v;
}
__device__ __forceinline__ float waveMax(float v) {
  #pragma unroll
  for (int o = 32; o > 0; o >>= 1) v = fmaxf(v, __shfl_down(v, o, 64));
  return v;
}

__global__ void k_reduce(const float* __restrict__ probs, const float* __restrict__ minf,
                         const float* __restrict__ minr, float* __restrict__ acc) {
  int tid = blockIdx.x * blockDim.x + threadIdx.x;
  int stride = gridDim.x * blockDim.x;
  float sf = 0.0f, sr = 0.0f, mx = 0.0f;
  for (int i = tid; i < NPTS; i += stride) {
    float d = sqrtf(fmaxf(minr[i], 1e-12f));
    sr = fmaf(probs[i >> 4], d, sr);
    mx = fmaxf(mx, d);
    if (i < G_F) {
      float df = sqrtf(fmaxf(minf[i], 1e-12f));
      sf = fmaf(probs[i], df, sf);
      sf = fmaf(1e-4f, 1.0f - probs[i], sf);
    }
  }
  __shared__ float lf[4], lr[4], lm[4];
  int lane = threadIdx.x & 63, wid = threadIdx.x >> 6;
  sf = waveSum(sf); sr = waveSum(sr); mx = waveMax(mx);
  if (lane == 0) { lf[wid] = sf; lr[wid] = sr; lm[wid] = mx; }
  __syncthreads();
  if (wid == 0) {
    float a = (lane < 4) ? lf[lane] : 0.0f;
    float b = (lane < 4) ? lr[lane] : 0.0f;
    float c = (lane < 4) ? lm[lane] : 0.0f;
    a = waveSum(a); b = waveSum(b); c = waveMax(c);
    if (lane == 0) {
      atomicAdd(&acc[0], a);
      atomicAdd(&acc[1], b);
      atomicMax((unsigned int*)&acc[2], __float_as_uint(c));
    }
  }
}

__global__ void k_final(const float* __restrict__ acc, float* __restrict__ out) {
  float maxd = acc[2] + 1e-8f;
  out[0] = acc[0] + acc[1] * 0.1f / maxd;
}

extern "C" void kernel_launch(void* const* d_in, const int* in_sizes, int n_in,
                              void* d_out, int out_size, void* d_ws, size_t ws_size,
                              hipStream_t stream) {
  const float* ov    = (const float*)d_in[0];
  const int*   of    = (const int*)  d_in[1];
  const float* sv    = (const float*)d_in[2];
  const int*   sfc   = (const int*)  d_in[3];
  const float* probs = (const float*)d_in[4];
  const float* r1    = (const float*)d_in[5];
  const float* r2    = (const float*)d_in[6];
  float*  ws  = (float*)d_ws;
  float4* ws4 = (float4*)d_ws;
  float*  out = (float*)d_out;

  float*        acc   = ws;
  float4*       sb4   = ws4 + F4_SB;
  float4*       pts4  = ws4 + F4_PTS;
  half8*        pkV   = (half8*)(ws4 + F4_PKV);
  half8*        pkO   = (half8*)(ws4 + F4_PKO);
  unsigned int* minfU = (unsigned int*)(ws + WS_MINF);
  unsigned int* minrU = (unsigned int*)(ws + WS_MINR);
  const float*  minfF = ws + WS_MINF;
  const float*  minrF = ws + WS_MINR;

  k_prep<<<NPTS/256, 256, 0, stream>>>(ov, of, sv, sfc, r1, r2,
                                       (unsigned int*)ws, ws4);
  // merged: x < 512 -> rev (131072 pts vs verts), x >= 512 -> fwd (8192
  // barycenters vs obary).  Both: 8 target strips x 4 chunks x 16 tiles.
  k_min<<<dim3(NPTS/256 + G_F/256, 8), 256, 0, stream>>>(
      pts4, pkV, minrU, sb4, pkO, minfU, 4);
  k_reduce<<<256, 256, 0, stream>>>(probs, minfF, minrF, acc);
  k_final<<<1, 1, 0, stream>>>(acc, out);
}